// Round 1
// baseline (399.371 us; speedup 1.0000x reference)
//
#include <hip/hip_runtime.h>
#include <hip/hip_bf16.h>
#include <math.h>

// ---------------------------------------------------------------------------
// RPN fused kernel for MI355X (gfx950)
//   trunk : 3x3 conv 64->512 + bias + relu   (fp16 single-pass MFMA)
//   heads : 1x1 conv 512->9 (sigmoid) and 512->36 (linear), deltas masked by
//           score > 0.7, output [B,H,W,45] fp32
// Round 8: trunk B-weights go global->VGPR (register double-buffer), killing
//   the LDS round-trip. Evidence: R6->R7 halved trunk MFMA for only +2.4% =>
//   trunk loop is bound by its memory machinery (20 LDS wave-ops + vmcnt(0)
//   + lgkmcnt(0) full drains per s-step), not the matrix pipe. B frags have
//   ZERO reuse (wave-private channel slice, each byte read once) so LDS
//   staging was pure overhead. New loop: prefetch B(s+1) into the spare reg
//   buffer while MFMA-ing B(s); compiler emits fine-grained waitcnts (no
//   manual drains). LDS ops per wave-step: 20 -> 4 (A-frags only; xs keeps
//   LDS since all 4 waves share it). Arena 52352 -> 49152 B (B-slots gone).
//   Numerics bit-identical to R7 (same MFMA sequence, same staging order).
// ---------------------------------------------------------------------------

typedef _Float16 fp16x8 __attribute__((ext_vector_type(8)));
typedef _Float16 fp16x4 __attribute__((ext_vector_type(4)));
typedef float    f32x4  __attribute__((ext_vector_type(4)));

#define BT_ELEMS  (18 * 32 * 64 * 8)    // 294912 trunk weights fp16
#define BT2_ELEMS (48 * 512)            // head weights, [o][k] k-major
#define BS_BYTES  32768                 // trunk weight bytes per s-step

// ---------------------------------------------------------------------------
// prep: trunk weights -> fp16 bt[s][j=wv*8+l][lane][8]  (frag-contiguous
//       order: wave w, frag l, lane, 8 k-elems); head weights -> fp16 hi/lo
// ---------------------------------------------------------------------------
__global__ __launch_bounds__(256) void rpn_prep(
    const float* __restrict__ wb,   // [3][3][64][512]
    const float* __restrict__ wc,   // [512][9]
    const float* __restrict__ wr,   // [512][36]
    _Float16* __restrict__ btI,
    _Float16* __restrict__ bt2_hi, _Float16* __restrict__ bt2_lo)
{
    int t = blockIdx.x * 256 + threadIdx.x;
    if (t < BT_ELEMS) {
        int e    = t & 7;
        int lane = (t >> 3) & 63;
        int j    = (t >> 9) & 31;
        int s    = t >> 14;              // 0..17
        int wv   = j >> 3, l = j & 7;
        int lr   = lane & 15, q = lane >> 4;
        int n    = wv * 128 + l * 16 + lr;
        int k    = s * 32 + q * 8 + e;   // 0..575
        int tap  = k >> 6, c = k & 63;   // k = (ky*3+kx)*64 + c
        btI[t] = (_Float16)wb[(tap * 64 + c) * 512 + n];
    } else if (t < BT_ELEMS + BT2_ELEMS) {
        int jj = t - BT_ELEMS;
        int k = jj & 511;
        int o = jj >> 9;                 // 0..47
        float v = 0.f;
        if (o < 9)       v = wc[k * 9 + o];
        else if (o < 45) v = wr[k * 36 + (o - 9)];
        _Float16 h = (_Float16)v;
        bt2_hi[jj] = h;
        bt2_lo[jj] = (_Float16)(v - (float)h);
    }
}

// ---------------------------------------------------------------------------
// main fused kernel: 4096 workgroups x 256 threads
//   tile = 64 output positions (2 h-rows x 32 w) x 512 channels
//   wave w owns channel slice [128w, 128w+128); acc[4][8] = 128 AGPR
// LDS arena (49152 B):
//   trunk phase: xs_hi [4][34][72] fp16 @ 0   (19584 B; shared by all waves)
//   head  phase (after barrier 2, xs dead):
//     zbuf float[64][48] @ 0 (12288 B)
//     fbuf per wave @ 12288 + w*9216 (fh [64][36] fp16, fl +4608 B)
// ---------------------------------------------------------------------------
#define FB_OFF      12288
#define FB_PER_WAVE 9216
#define ARENA_BYTES 49152

// one trunk s-step: 4 A-frags from shared xs, 32 MFMAs from registers
#define TRUNK_STEP(S, BREG)                                                   \
    {                                                                         \
        const int tap_ = (S) >> 1;                                            \
        const int ky_  = tap_ / 3;                                            \
        const int kx_  = tap_ - ky_ * 3;                                      \
        const int c0_  = ((S) & 1) * 32 + q * 8;                              \
        fp16x8 ah[4];                                                         \
        _Pragma("unroll")                                                     \
        for (int km = 0; km < 4; ++km) {                                      \
            int rowp = (km >> 1) + ky_;                                       \
            int pos  = ((km & 1) << 4) + lr + kx_;                            \
            ah[km] = *(const fp16x8*)&xs_hi[(rowp * 34 + pos) * 72 + c0_];    \
        }                                                                     \
        _Pragma("unroll")                                                     \
        for (int l = 0; l < 8; ++l) {                                         \
            acc[0][l] = __builtin_amdgcn_mfma_f32_16x16x32_f16(ah[0], BREG[l], acc[0][l], 0, 0, 0); \
            acc[1][l] = __builtin_amdgcn_mfma_f32_16x16x32_f16(ah[1], BREG[l], acc[1][l], 0, 0, 0); \
            acc[2][l] = __builtin_amdgcn_mfma_f32_16x16x32_f16(ah[2], BREG[l], acc[2][l], 0, 0, 0); \
            acc[3][l] = __builtin_amdgcn_mfma_f32_16x16x32_f16(ah[3], BREG[l], acc[3][l], 0, 0, 0); \
        }                                                                     \
    }

__global__ __launch_bounds__(256, 2) void rpn_main(
    const float* __restrict__ x,        // [4][256][256][64]
    const float* __restrict__ b_base,   // [512]
    const float* __restrict__ b_cls,    // [9]
    const float* __restrict__ b_reg,    // [36]
    const _Float16* __restrict__ btI,
    const _Float16* __restrict__ bt2_hi, const _Float16* __restrict__ bt2_lo,
    float* __restrict__ out)            // [4][256][256][45]
{
    __shared__ char smem[ARENA_BYTES];
    _Float16* xs_hi = (_Float16*)smem;          // trunk phase only
    float*    zbuf  = (float*)smem;             // head phase only

    const int tid  = threadIdx.x;
    const int wave = tid >> 6;
    const int lane = tid & 63;
    const int q    = lane >> 4;     // 0..3
    const int lr   = lane & 15;     // 0..15
    const int n0   = wave * 128;    // wave's channel-slice base

    const int wg  = blockIdx.x;
    const int b   = wg >> 10;           // 1024 tiles per image
    const int rem = wg & 1023;
    const int h0  = (rem >> 3) * 2;     // 2 h-rows per tile
    const int w0  = (rem & 7) * 32;     // 32 w-positions per tile

    // wave's B-frag base in global: frag (s,wave,l,lane) at
    //   s*32768 + wave*8192 + l*1024 + lane*16 bytes
    const char* gW = (const char*)btI + wave * 8192 + lane * 16;

    // ---- issue B(s=0) into registers first: latency overlaps x staging ----
    fp16x8 bA[8], bB[8];
    #pragma unroll
    for (int l = 0; l < 8; ++l)
        bA[l] = *(const fp16x8*)(gW + (size_t)l * 1024);

    // ---- stage x patch (4 rows x 34 pos x 64 ch) as fp16 (shared, 4x reuse) ----
    for (int i = 0; i < 9; ++i) {
        int flat = tid + i * 256;
        if (flat < 4 * 34 * 16) {
            int cq  = flat & 15;          // channel quad
            int rp  = flat >> 4;          // 0..135
            int row = rp / 34;
            int pos = rp - row * 34;
            int hh  = h0 - 1 + row;
            int ww  = w0 - 1 + pos;
            fp16x4 h4;
            if (hh >= 0 && hh < 256 && ww >= 0 && ww < 256) {
                const float4 v = *(const float4*)&x[(((b * 256 + hh) * 256 + ww) * 64 + cq * 4)];
                h4[0] = (_Float16)v.x; h4[1] = (_Float16)v.y;
                h4[2] = (_Float16)v.z; h4[3] = (_Float16)v.w;
            } else {
                #pragma unroll
                for (int j = 0; j < 4; ++j) h4[j] = (_Float16)0.f;
            }
            *(fp16x4*)&xs_hi[(row * 34 + pos) * 72 + cq * 4] = h4;
        }
    }
    __syncthreads();   // barrier 1: xs ready (all waves read all of it)

    // ---- trunk K-loop: 18 s-steps, barrier-free, reg-double-buffered B ----
    // Prefetch B(s+1) while MFMA-ing B(s); no LDS round-trip, no full
    // vmcnt/lgkmcnt drains -- compiler inserts fine-grained waits per frag.
    f32x4 acc[4][8];
    #pragma unroll
    for (int km = 0; km < 4; ++km)
        #pragma unroll
        for (int l = 0; l < 8; ++l)
            acc[km][l] = (f32x4){0.f, 0.f, 0.f, 0.f};

    for (int s = 0; s < 18; s += 2) {
        {   // prefetch s+1 -> bB (always exists: s+1 <= 17)
            const char* g1 = gW + (size_t)(s + 1) * BS_BYTES;
            #pragma unroll
            for (int l = 0; l < 8; ++l)
                bB[l] = *(const fp16x8*)(g1 + (size_t)l * 1024);
        }
        TRUNK_STEP(s, bA);
        if (s + 2 < 18) {   // prefetch s+2 -> bA
            const char* g2 = gW + (size_t)(s + 2) * BS_BYTES;
            #pragma unroll
            for (int l = 0; l < 8; ++l)
                bA[l] = *(const fp16x8*)(g2 + (size_t)l * 1024);
        }
        TRUNK_STEP(s + 1, bB);
    }

    __syncthreads();   // barrier 2: trunk done, xs dead, arena reusable

    // ---- fused 1x1 heads: per-wave k-slice GEMM feat[64][128] x w2[128][48] ----
    _Float16* fh = (_Float16*)(smem + FB_OFF + wave * FB_PER_WAVE);
    _Float16* fl = fh + 64 * 36;

    f32x4 acc2[4][3];
    #pragma unroll
    for (int km = 0; km < 4; ++km)
        #pragma unroll
        for (int ns = 0; ns < 3; ++ns)
            acc2[km][ns] = (f32x4){0.f, 0.f, 0.f, 0.f};

    for (int sub = 0; sub < 4; ++sub) {       // 4 k-chunks of 32 within the slice
        // dump this wave's 32-channel slice of feat (bias+relu, fp16 hi/lo)
        #pragma unroll
        for (int lh = 0; lh < 2; ++lh) {
            int l = sub * 2 + lh;
            float bias = b_base[n0 + l * 16 + lr];
            #pragma unroll
            for (int km = 0; km < 4; ++km) {
                #pragma unroll
                for (int r = 0; r < 4; ++r) {
                    float v = acc[km][l][r] + bias;
                    v = v > 0.f ? v : 0.f;
                    _Float16 h = (_Float16)v;
                    int row = km * 16 + q * 4 + r;
                    int col = lh * 16 + lr;
                    fh[row * 36 + col] = h;
                    fl[row * 36 + col] = (_Float16)(v - (float)h);
                }
            }
        }
        asm volatile("s_waitcnt lgkmcnt(0)" ::: "memory");  // wave-local RAW fence

        // A-frags: feat rows, k-local = q*8..q*8+7 (8-byte aligned -> 2x b64)
        fp16x8 fah[4], fal[4];
        #pragma unroll
        for (int km = 0; km < 4; ++km) {
            int off = (km * 16 + lr) * 36 + q * 8;
            union { fp16x8 v8; fp16x4 v4[2]; } uh, ul;
            uh.v4[0] = *(const fp16x4*)&fh[off];
            uh.v4[1] = *(const fp16x4*)&fh[off + 4];
            ul.v4[0] = *(const fp16x4*)&fl[off];
            ul.v4[1] = *(const fp16x4*)&fl[off + 4];
            fah[km] = uh.v8;
            fal[km] = ul.v8;
        }

        const int kg = n0 + sub * 32 + q * 8;   // global k for B frags
        // ns = 0 (contains the 9 score cols): 3-pass hi/lo
        {
            int eo = (0 * 16 + lr) * 512 + kg;
            fp16x8 wh = *(const fp16x8*)&bt2_hi[eo];
            fp16x8 wl = *(const fp16x8*)&bt2_lo[eo];
            #pragma unroll
            for (int km = 0; km < 4; ++km)
                acc2[km][0] = __builtin_amdgcn_mfma_f32_16x16x32_f16(fah[km], wh, acc2[km][0], 0, 0, 0);
            #pragma unroll
            for (int km = 0; km < 4; ++km)
                acc2[km][0] = __builtin_amdgcn_mfma_f32_16x16x32_f16(fah[km], wl, acc2[km][0], 0, 0, 0);
            #pragma unroll
            for (int km = 0; km < 4; ++km)
                acc2[km][0] = __builtin_amdgcn_mfma_f32_16x16x32_f16(fal[km], wh, acc2[km][0], 0, 0, 0);
        }
        // ns = 1,2 (pure delta cols): 2-pass (w fp16 single, feat hi+lo)
        #pragma unroll
        for (int ns = 1; ns < 3; ++ns) {
            int eo = (ns * 16 + lr) * 512 + kg;
            fp16x8 wh = *(const fp16x8*)&bt2_hi[eo];
            #pragma unroll
            for (int km = 0; km < 4; ++km)
                acc2[km][ns] = __builtin_amdgcn_mfma_f32_16x16x32_f16(fah[km], wh, acc2[km][ns], 0, 0, 0);
            #pragma unroll
            for (int km = 0; km < 4; ++km)
                acc2[km][ns] = __builtin_amdgcn_mfma_f32_16x16x32_f16(fal[km], wh, acc2[km][ns], 0, 0, 0);
        }
    }

    // ---- deterministic staged cross-wave k-reduction (fixed FP order ->
    //      bitwise-identical output every launch) ----
    for (int w = 0; w < 4; ++w) {
        if (wave == w) {
            #pragma unroll
            for (int km = 0; km < 4; ++km)
                #pragma unroll
                for (int ns = 0; ns < 3; ++ns)
                    #pragma unroll
                    for (int r = 0; r < 4; ++r) {
                        int row = km * 16 + q * 4 + r;
                        int col = ns * 16 + lr;
                        float v = acc2[km][ns][r];
                        if (w == 0) zbuf[row * 48 + col] = v;
                        else        zbuf[row * 48 + col] += v;
                    }
        }
        __syncthreads();   // stage w complete before stage w+1 / epilogue
    }

    // ---- epilogue: sigmoid, threshold mask, store ----
    for (int i = tid; i < 64 * 45; i += 256) {
        int m = i / 45;
        int o = i - m * 45;
        float z = zbuf[m * 48 + o];
        float v;
        if (o < 9) {
            v = 1.f / (1.f + expf(-(z + b_cls[o])));
        } else {
            int d = o - 9;
            int a = d >> 2;
            float s = 1.f / (1.f + expf(-(zbuf[m * 48 + a] + b_cls[a])));
            v = (s > 0.7f) ? (z + b_reg[d]) : 0.f;
        }
        int mh = m >> 5, mw = m & 31;
        out[(((b * 256 + h0 + mh) * 256) + w0 + mw) * 45 + o] = v;
    }
}

// ---------------------------------------------------------------------------
extern "C" void kernel_launch(void* const* d_in, const int* in_sizes, int n_in,
                              void* d_out, int out_size, void* d_ws, size_t ws_size,
                              hipStream_t stream)
{
    const float* x      = (const float*)d_in[0];
    const float* w_base = (const float*)d_in[1];
    const float* b_base = (const float*)d_in[2];
    const float* w_cls  = (const float*)d_in[3];
    const float* b_cls  = (const float*)d_in[4];
    const float* w_reg  = (const float*)d_in[5];
    const float* b_reg  = (const float*)d_in[6];
    float* out = (float*)d_out;

    _Float16* btI    = (_Float16*)d_ws;
    _Float16* bt2_hi = btI + BT_ELEMS;
    _Float16* bt2_lo = bt2_hi + BT2_ELEMS;

    rpn_prep<<<(BT_ELEMS + BT2_ELEMS + 255) / 256, 256, 0, stream>>>(
        w_base, w_cls, w_reg, btI, bt2_hi, bt2_lo);
    rpn_main<<<4096, 256, 0, stream>>>(
        x, b_base, b_cls, b_reg, btI, bt2_hi, bt2_lo, out);
}

// Round 4
// 392.462 us; speedup vs baseline: 1.0176x; 1.0176x over previous
//
#include <hip/hip_runtime.h>
#include <hip/hip_bf16.h>
#include <math.h>

// ---------------------------------------------------------------------------
// RPN fused kernel for MI355X (gfx950)
//   trunk : 3x3 conv 64->512 + bias + relu   (fp16 single-pass MFMA)
//   heads : 1x1 conv 512->9 (sigmoid) and 512->36 (linear), deltas masked by
//           score > 0.7, output [B,H,W,45] fp32
// Round 9 (2nd resubmit; R1/R2 benches lost to GPU-acquisition timeouts):
//   occupancy retile. R8 counters: MfmaUtil 22.6 / VALUBusy 23.3 /
//   Occupancy 22.3 / HBM 3% / L2 ~20% -- NOTHING saturated => latency-bound
//   at 2 waves/SIMD (256-reg waves: acc[4][8]=128 AGPR). Three consecutive
//   trunk-work cuts (R6-R8) moved <5% each, consistent with that diagnosis.
//   Fix: halve the position tile (2h x 16w = 32 pos, 8192 blocks) so
//   acc -> [2][8] = 64 regs; per-wave total ~150 -> __launch_bounds__(256,3)
//   gives 3 waves/SIMD (+50% latency hiding). Arena 49152 -> 24576 B.
//   Per-output arithmetic order is bitwise-identical to R8.
// ---------------------------------------------------------------------------

typedef _Float16 fp16x8 __attribute__((ext_vector_type(8)));
typedef _Float16 fp16x4 __attribute__((ext_vector_type(4)));
typedef float    f32x4  __attribute__((ext_vector_type(4)));

#define BT_ELEMS  (18 * 32 * 64 * 8)    // 294912 trunk weights fp16
#define BT2_ELEMS (48 * 512)            // head weights, [o][k] k-major
#define BS_BYTES  32768                 // trunk weight bytes per s-step

// ---------------------------------------------------------------------------
// prep: trunk weights -> fp16 bt[s][j=wv*8+l][lane][8]; head weights hi/lo.
// (unchanged from R8)
// ---------------------------------------------------------------------------
__global__ __launch_bounds__(256) void rpn_prep(
    const float* __restrict__ wb,   // [3][3][64][512]
    const float* __restrict__ wc,   // [512][9]
    const float* __restrict__ wr,   // [512][36]
    _Float16* __restrict__ btI,
    _Float16* __restrict__ bt2_hi, _Float16* __restrict__ bt2_lo)
{
    int t = blockIdx.x * 256 + threadIdx.x;
    if (t < BT_ELEMS) {
        int e    = t & 7;
        int lane = (t >> 3) & 63;
        int j    = (t >> 9) & 31;
        int s    = t >> 14;              // 0..17
        int wv   = j >> 3, l = j & 7;
        int lr   = lane & 15, q = lane >> 4;
        int n    = wv * 128 + l * 16 + lr;
        int k    = s * 32 + q * 8 + e;   // 0..575
        int tap  = k >> 6, c = k & 63;   // k = (ky*3+kx)*64 + c
        btI[t] = (_Float16)wb[(tap * 64 + c) * 512 + n];
    } else if (t < BT_ELEMS + BT2_ELEMS) {
        int jj = t - BT_ELEMS;
        int k = jj & 511;
        int o = jj >> 9;                 // 0..47
        float v = 0.f;
        if (o < 9)       v = wc[k * 9 + o];
        else if (o < 45) v = wr[k * 36 + (o - 9)];
        _Float16 h = (_Float16)v;
        bt2_hi[jj] = h;
        bt2_lo[jj] = (_Float16)(v - (float)h);
    }
}

// ---------------------------------------------------------------------------
// main fused kernel: 8192 workgroups x 256 threads
//   tile = 32 output positions (2 h-rows x 16 w) x 512 channels
//   wave w owns channel slice [128w, 128w+128); acc[2][8] = 64 AGPR
// LDS arena (24576 B):
//   trunk phase: xs_hi [4][18][72] fp16 @ 0   (10368 B; shared by all waves)
//   head  phase (after barrier 2, xs dead):
//     zbuf float[32][48] @ 0 (6144 B)
//     fbuf per wave @ 6144 + w*4608 (fh [32][36] fp16, fl +2304 B)
// ---------------------------------------------------------------------------
#define FB_OFF      6144
#define FB_PER_WAVE 4608
#define ARENA_BYTES 24576

// one trunk s-step: 2 A-frags from shared xs, 16 MFMAs from registers
#define TRUNK_STEP(S, BREG)                                                   \
    {                                                                         \
        const int tap_ = (S) >> 1;                                            \
        const int ky_  = tap_ / 3;                                            \
        const int kx_  = tap_ - ky_ * 3;                                      \
        const int c0_  = ((S) & 1) * 32 + q * 8;                              \
        fp16x8 ah[2];                                                         \
        _Pragma("unroll")                                                     \
        for (int km = 0; km < 2; ++km) {                                      \
            int rowp = km + ky_;                                              \
            int pos  = lr + kx_;                                              \
            ah[km] = *(const fp16x8*)&xs_hi[(rowp * 18 + pos) * 72 + c0_];    \
        }                                                                     \
        _Pragma("unroll")                                                     \
        for (int l = 0; l < 8; ++l) {                                         \
            acc[0][l] = __builtin_amdgcn_mfma_f32_16x16x32_f16(ah[0], BREG[l], acc[0][l], 0, 0, 0); \
            acc[1][l] = __builtin_amdgcn_mfma_f32_16x16x32_f16(ah[1], BREG[l], acc[1][l], 0, 0, 0); \
        }                                                                     \
    }

__global__ __launch_bounds__(256, 3) void rpn_main(
    const float* __restrict__ x,        // [4][256][256][64]
    const float* __restrict__ b_base,   // [512]
    const float* __restrict__ b_cls,    // [9]
    const float* __restrict__ b_reg,    // [36]
    const _Float16* __restrict__ btI,
    const _Float16* __restrict__ bt2_hi, const _Float16* __restrict__ bt2_lo,
    float* __restrict__ out)            // [4][256][256][45]
{
    __shared__ char smem[ARENA_BYTES];
    _Float16* xs_hi = (_Float16*)smem;          // trunk phase only
    float*    zbuf  = (float*)smem;             // head phase only

    const int tid  = threadIdx.x;
    const int wave = tid >> 6;
    const int lane = tid & 63;
    const int q    = lane >> 4;     // 0..3
    const int lr   = lane & 15;     // 0..15
    const int n0   = wave * 128;    // wave's channel-slice base

    const int wg  = blockIdx.x;
    const int b   = wg >> 11;           // 2048 tiles per image
    const int rem = wg & 2047;
    const int h0  = (rem >> 4) * 2;     // 2 h-rows per tile
    const int w0  = (rem & 15) * 16;    // 16 w-positions per tile

    // wave's B-frag base in global: frag (s,wave,l,lane) at
    //   s*32768 + wave*8192 + l*1024 + lane*16 bytes
    const char* gW = (const char*)btI + wave * 8192 + lane * 16;

    // ---- issue B(s=0) into registers first: latency overlaps x staging ----
    fp16x8 bA[8], bB[8];
    #pragma unroll
    for (int l = 0; l < 8; ++l)
        bA[l] = *(const fp16x8*)(gW + (size_t)l * 1024);

    // ---- stage x patch (4 rows x 18 pos x 64 ch) as fp16 (shared, 4x reuse) ----
    for (int i = 0; i < 5; ++i) {
        int flat = tid + i * 256;
        if (flat < 4 * 18 * 16) {
            int cq  = flat & 15;          // channel quad
            int rp  = flat >> 4;          // 0..71
            int row = rp / 18;
            int pos = rp - row * 18;
            int hh  = h0 - 1 + row;
            int ww  = w0 - 1 + pos;
            fp16x4 h4;
            if (hh >= 0 && hh < 256 && ww >= 0 && ww < 256) {
                const float4 v = *(const float4*)&x[(((b * 256 + hh) * 256 + ww) * 64 + cq * 4)];
                h4[0] = (_Float16)v.x; h4[1] = (_Float16)v.y;
                h4[2] = (_Float16)v.z; h4[3] = (_Float16)v.w;
            } else {
                #pragma unroll
                for (int j = 0; j < 4; ++j) h4[j] = (_Float16)0.f;
            }
            *(fp16x4*)&xs_hi[(row * 18 + pos) * 72 + cq * 4] = h4;
        }
    }
    __syncthreads();   // barrier 1: xs ready (all waves read all of it)

    // ---- trunk K-loop: 18 s-steps, barrier-free, reg-double-buffered B ----
    f32x4 acc[2][8];
    #pragma unroll
    for (int km = 0; km < 2; ++km)
        #pragma unroll
        for (int l = 0; l < 8; ++l)
            acc[km][l] = (f32x4){0.f, 0.f, 0.f, 0.f};

    for (int s = 0; s < 18; s += 2) {
        {   // prefetch s+1 -> bB (always exists: s+1 <= 17)
            const char* g1 = gW + (size_t)(s + 1) * BS_BYTES;
            #pragma unroll
            for (int l = 0; l < 8; ++l)
                bB[l] = *(const fp16x8*)(g1 + (size_t)l * 1024);
        }
        TRUNK_STEP(s, bA);
        if (s + 2 < 18) {   // prefetch s+2 -> bA
            const char* g2 = gW + (size_t)(s + 2) * BS_BYTES;
            #pragma unroll
            for (int l = 0; l < 8; ++l)
                bA[l] = *(const fp16x8*)(g2 + (size_t)l * 1024);
        }
        TRUNK_STEP(s + 1, bB);
    }

    __syncthreads();   // barrier 2: trunk done, xs dead, arena reusable

    // ---- fused 1x1 heads: per-wave k-slice GEMM feat[32][128] x w2[128][48] ----
    _Float16* fh = (_Float16*)(smem + FB_OFF + wave * FB_PER_WAVE);
    _Float16* fl = fh + 32 * 36;

    f32x4 acc2[2][3];
    #pragma unroll
    for (int km = 0; km < 2; ++km)
        #pragma unroll
        for (int ns = 0; ns < 3; ++ns)
            acc2[km][ns] = (f32x4){0.f, 0.f, 0.f, 0.f};

    for (int sub = 0; sub < 4; ++sub) {       // 4 k-chunks of 32 within the slice
        // dump this wave's 32-channel slice of feat (bias+relu, fp16 hi/lo)
        #pragma unroll
        for (int lh = 0; lh < 2; ++lh) {
            int l = sub * 2 + lh;
            float bias = b_base[n0 + l * 16 + lr];
            #pragma unroll
            for (int km = 0; km < 2; ++km) {
                #pragma unroll
                for (int r = 0; r < 4; ++r) {
                    float v = acc[km][l][r] + bias;
                    v = v > 0.f ? v : 0.f;
                    _Float16 h = (_Float16)v;
                    int row = km * 16 + q * 4 + r;
                    int col = lh * 16 + lr;
                    fh[row * 36 + col] = h;
                    fl[row * 36 + col] = (_Float16)(v - (float)h);
                }
            }
        }
        asm volatile("s_waitcnt lgkmcnt(0)" ::: "memory");  // wave-local RAW fence

        // A-frags: feat rows, k-local = q*8..q*8+7 (8-byte aligned -> 2x b64)
        fp16x8 fah[2], fal[2];
        #pragma unroll
        for (int km = 0; km < 2; ++km) {
            int off = (km * 16 + lr) * 36 + q * 8;
            union { fp16x8 v8; fp16x4 v4[2]; } uh, ul;
            uh.v4[0] = *(const fp16x4*)&fh[off];
            uh.v4[1] = *(const fp16x4*)&fh[off + 4];
            ul.v4[0] = *(const fp16x4*)&fl[off];
            ul.v4[1] = *(const fp16x4*)&fl[off + 4];
            fah[km] = uh.v8;
            fal[km] = ul.v8;
        }

        const int kg = n0 + sub * 32 + q * 8;   // global k for B frags
        // ns = 0 (contains the 9 score cols): 3-pass hi/lo
        {
            int eo = (0 * 16 + lr) * 512 + kg;
            fp16x8 wh = *(const fp16x8*)&bt2_hi[eo];
            fp16x8 wl = *(const fp16x8*)&bt2_lo[eo];
            #pragma unroll
            for (int km = 0; km < 2; ++km)
                acc2[km][0] = __builtin_amdgcn_mfma_f32_16x16x32_f16(fah[km], wh, acc2[km][0], 0, 0, 0);
            #pragma unroll
            for (int km = 0; km < 2; ++km)
                acc2[km][0] = __builtin_amdgcn_mfma_f32_16x16x32_f16(fah[km], wl, acc2[km][0], 0, 0, 0);
            #pragma unroll
            for (int km = 0; km < 2; ++km)
                acc2[km][0] = __builtin_amdgcn_mfma_f32_16x16x32_f16(fal[km], wh, acc2[km][0], 0, 0, 0);
        }
        // ns = 1,2 (pure delta cols): 2-pass (w fp16 single, feat hi+lo)
        #pragma unroll
        for (int ns = 1; ns < 3; ++ns) {
            int eo = (ns * 16 + lr) * 512 + kg;
            fp16x8 wh = *(const fp16x8*)&bt2_hi[eo];
            #pragma unroll
            for (int km = 0; km < 2; ++km)
                acc2[km][ns] = __builtin_amdgcn_mfma_f32_16x16x32_f16(fah[km], wh, acc2[km][ns], 0, 0, 0);
            #pragma unroll
            for (int km = 0; km < 2; ++km)
                acc2[km][ns] = __builtin_amdgcn_mfma_f32_16x16x32_f16(fal[km], wh, acc2[km][ns], 0, 0, 0);
        }
    }

    // ---- deterministic staged cross-wave k-reduction (fixed FP order ->
    //      bitwise-identical output every launch) ----
    for (int w = 0; w < 4; ++w) {
        if (wave == w) {
            #pragma unroll
            for (int km = 0; km < 2; ++km)
                #pragma unroll
                for (int ns = 0; ns < 3; ++ns)
                    #pragma unroll
                    for (int r = 0; r < 4; ++r) {
                        int row = km * 16 + q * 4 + r;
                        int col = ns * 16 + lr;
                        float v = acc2[km][ns][r];
                        if (w == 0) zbuf[row * 48 + col] = v;
                        else        zbuf[row * 48 + col] += v;
                    }
        }
        __syncthreads();   // stage w complete before stage w+1 / epilogue
    }

    // ---- epilogue: sigmoid, threshold mask, store ----
    for (int i = tid; i < 32 * 45; i += 256) {
        int m = i / 45;
        int o = i - m * 45;
        float z = zbuf[m * 48 + o];
        float v;
        if (o < 9) {
            v = 1.f / (1.f + expf(-(z + b_cls[o])));
        } else {
            int d = o - 9;
            int a = d >> 2;
            float s = 1.f / (1.f + expf(-(zbuf[m * 48 + a] + b_cls[a])));
            v = (s > 0.7f) ? (z + b_reg[d]) : 0.f;
        }
        int mh = m >> 4, mw = m & 15;
        out[(((b * 256 + h0 + mh) * 256) + w0 + mw) * 45 + o] = v;
    }
}

// ---------------------------------------------------------------------------
extern "C" void kernel_launch(void* const* d_in, const int* in_sizes, int n_in,
                              void* d_out, int out_size, void* d_ws, size_t ws_size,
                              hipStream_t stream)
{
    const float* x      = (const float*)d_in[0];
    const float* w_base = (const float*)d_in[1];
    const float* b_base = (const float*)d_in[2];
    const float* w_cls  = (const float*)d_in[3];
    const float* b_cls  = (const float*)d_in[4];
    const float* w_reg  = (const float*)d_in[5];
    const float* b_reg  = (const float*)d_in[6];
    float* out = (float*)d_out;

    _Float16* btI    = (_Float16*)d_ws;
    _Float16* bt2_hi = btI + BT_ELEMS;
    _Float16* bt2_lo = bt2_hi + BT2_ELEMS;

    rpn_prep<<<(BT_ELEMS + BT2_ELEMS + 255) / 256, 256, 0, stream>>>(
        w_base, w_cls, w_reg, btI, bt2_hi, bt2_lo);
    rpn_main<<<8192, 256, 0, stream>>>(
        x, b_base, b_cls, b_reg, btI, bt2_hi, bt2_lo, out);
}

// Round 5
// 360.624 us; speedup vs baseline: 1.1074x; 1.0883x over previous
//
#include <hip/hip_runtime.h>
#include <hip/hip_bf16.h>
#include <math.h>

// ---------------------------------------------------------------------------
// RPN fused kernel for MI355X (gfx950)
//   trunk : 3x3 conv 64->512 + bias + relu   (fp16 single-pass MFMA)
//   heads : 1x1 conv 512->9 (sigmoid) and 512->36 (linear), deltas masked by
//           score > 0.7, output [B,H,W,45] fp32
// Round 10: stall-reduction bundle. R9 post-mortem: occupancy 22->45% moved
//   dur only -3% => not occupancy-bound. Corrected MFMA cost model
//   (16x16x32 = ~19.4 SIMD-cyc, not 4.85) makes all counters consistent:
//   MFMA floor ~89us, ~50% of wave lifetime is dependency stalls.
//   Changes (FP order bitwise-identical to R9):
//   1) xs stride 72->76 fp16: old dword-stride 36 put 64 lanes on 8 banks
//      (4x serialization on EVERY trunk A ds_read_b128, on the critical
//      chain; ~all of the 6.15M SQ_LDS_BANK_CONFLICT). Stride 38 dwords
//      spreads windows over all even banks -> 2-way = free.
//   2) serial 4-stage zbuf reduction (4 barriers, 3/4 waves idle, LDS RMW)
//      -> concurrent per-wave partial slices [4][32][50] + 2 barriers;
//      epilogue sums ((w0+w1)+w2)+w3 (same order -> bitwise identical).
//   3) s_setprio(1) around trunk MFMA cluster (T5; blocks at different
//      phases give the CU scheduler something to arbitrate).
// ---------------------------------------------------------------------------

typedef _Float16 fp16x8 __attribute__((ext_vector_type(8)));
typedef _Float16 fp16x4 __attribute__((ext_vector_type(4)));
typedef float    f32x4  __attribute__((ext_vector_type(4)));

#define BT_ELEMS  (18 * 32 * 64 * 8)    // 294912 trunk weights fp16
#define BT2_ELEMS (48 * 512)            // head weights, [o][k] k-major
#define BS_BYTES  32768                 // trunk weight bytes per s-step

// ---------------------------------------------------------------------------
// prep: trunk weights -> fp16 bt[s][j=wv*8+l][lane][8]; head weights hi/lo.
// (unchanged)
// ---------------------------------------------------------------------------
__global__ __launch_bounds__(256) void rpn_prep(
    const float* __restrict__ wb,   // [3][3][64][512]
    const float* __restrict__ wc,   // [512][9]
    const float* __restrict__ wr,   // [512][36]
    _Float16* __restrict__ btI,
    _Float16* __restrict__ bt2_hi, _Float16* __restrict__ bt2_lo)
{
    int t = blockIdx.x * 256 + threadIdx.x;
    if (t < BT_ELEMS) {
        int e    = t & 7;
        int lane = (t >> 3) & 63;
        int j    = (t >> 9) & 31;
        int s    = t >> 14;              // 0..17
        int wv   = j >> 3, l = j & 7;
        int lr   = lane & 15, q = lane >> 4;
        int n    = wv * 128 + l * 16 + lr;
        int k    = s * 32 + q * 8 + e;   // 0..575
        int tap  = k >> 6, c = k & 63;   // k = (ky*3+kx)*64 + c
        btI[t] = (_Float16)wb[(tap * 64 + c) * 512 + n];
    } else if (t < BT_ELEMS + BT2_ELEMS) {
        int jj = t - BT_ELEMS;
        int k = jj & 511;
        int o = jj >> 9;                 // 0..47
        float v = 0.f;
        if (o < 9)       v = wc[k * 9 + o];
        else if (o < 45) v = wr[k * 36 + (o - 9)];
        _Float16 h = (_Float16)v;
        bt2_hi[jj] = h;
        bt2_lo[jj] = (_Float16)(v - (float)h);
    }
}

// ---------------------------------------------------------------------------
// main fused kernel: 8192 workgroups x 256 threads
//   tile = 32 output positions (2 h-rows x 16 w) x 512 channels
//   wave w owns channel slice [128w, 128w+128); acc[2][8] = 64 AGPR
// LDS arena (25600 B):
//   trunk phase: xs_hi [4][18][76] fp16 @ 0   (10944 B; shared by all waves)
//   head  phase (after barrier 2, xs dead):
//     fbuf per wave @ w*4608 (fh [32][36] fp16, fl +2304 B)   [0, 18432)
//   reduction (after barrier 3, fbuf dead):
//     zbuf4 [4][32][50] f32 @ 0   (25600 B; wave w owns slice w)
// ---------------------------------------------------------------------------
#define XS_STRIDE   76
#define FB_PER_WAVE 4608
#define ZB_SLICE    1600                 // floats per wave slice (32*50)
#define ARENA_BYTES 25600

// one trunk s-step: 2 A-frags from shared xs, 16 MFMAs from registers
#define TRUNK_STEP(S, BREG)                                                   \
    {                                                                         \
        const int tap_ = (S) >> 1;                                            \
        const int ky_  = tap_ / 3;                                            \
        const int kx_  = tap_ - ky_ * 3;                                      \
        const int c0_  = ((S) & 1) * 32 + q * 8;                              \
        fp16x8 ah[2];                                                         \
        _Pragma("unroll")                                                     \
        for (int km = 0; km < 2; ++km) {                                      \
            int rowp = km + ky_;                                              \
            int pos  = lr + kx_;                                              \
            ah[km] = *(const fp16x8*)&xs_hi[(rowp * 18 + pos) * XS_STRIDE + c0_]; \
        }                                                                     \
        __builtin_amdgcn_s_setprio(1);                                        \
        _Pragma("unroll")                                                     \
        for (int l = 0; l < 8; ++l) {                                         \
            acc[0][l] = __builtin_amdgcn_mfma_f32_16x16x32_f16(ah[0], BREG[l], acc[0][l], 0, 0, 0); \
            acc[1][l] = __builtin_amdgcn_mfma_f32_16x16x32_f16(ah[1], BREG[l], acc[1][l], 0, 0, 0); \
        }                                                                     \
        __builtin_amdgcn_s_setprio(0);                                        \
    }

__global__ __launch_bounds__(256, 3) void rpn_main(
    const float* __restrict__ x,        // [4][256][256][64]
    const float* __restrict__ b_base,   // [512]
    const float* __restrict__ b_cls,    // [9]
    const float* __restrict__ b_reg,    // [36]
    const _Float16* __restrict__ btI,
    const _Float16* __restrict__ bt2_hi, const _Float16* __restrict__ bt2_lo,
    float* __restrict__ out)            // [4][256][256][45]
{
    __shared__ char smem[ARENA_BYTES];
    _Float16* xs_hi = (_Float16*)smem;          // trunk phase only
    float*    zb    = (float*)smem;             // reduction phase only

    const int tid  = threadIdx.x;
    const int wave = tid >> 6;
    const int lane = tid & 63;
    const int q    = lane >> 4;     // 0..3
    const int lr   = lane & 15;     // 0..15
    const int n0   = wave * 128;    // wave's channel-slice base

    const int wg  = blockIdx.x;
    const int b   = wg >> 11;           // 2048 tiles per image
    const int rem = wg & 2047;
    const int h0  = (rem >> 4) * 2;     // 2 h-rows per tile
    const int w0  = (rem & 15) * 16;    // 16 w-positions per tile

    // wave's B-frag base in global: frag (s,wave,l,lane) at
    //   s*32768 + wave*8192 + l*1024 + lane*16 bytes
    const char* gW = (const char*)btI + wave * 8192 + lane * 16;

    // ---- issue B(s=0) into registers first: latency overlaps x staging ----
    fp16x8 bA[8], bB[8];
    #pragma unroll
    for (int l = 0; l < 8; ++l)
        bA[l] = *(const fp16x8*)(gW + (size_t)l * 1024);

    // ---- stage x patch (4 rows x 18 pos x 64 ch) as fp16 (shared, 4x reuse) ----
    for (int i = 0; i < 5; ++i) {
        int flat = tid + i * 256;
        if (flat < 4 * 18 * 16) {
            int cq  = flat & 15;          // channel quad
            int rp  = flat >> 4;          // 0..71
            int row = rp / 18;
            int pos = rp - row * 18;
            int hh  = h0 - 1 + row;
            int ww  = w0 - 1 + pos;
            fp16x4 h4;
            if (hh >= 0 && hh < 256 && ww >= 0 && ww < 256) {
                const float4 v = *(const float4*)&x[(((b * 256 + hh) * 256 + ww) * 64 + cq * 4)];
                h4[0] = (_Float16)v.x; h4[1] = (_Float16)v.y;
                h4[2] = (_Float16)v.z; h4[3] = (_Float16)v.w;
            } else {
                #pragma unroll
                for (int j = 0; j < 4; ++j) h4[j] = (_Float16)0.f;
            }
            *(fp16x4*)&xs_hi[(row * 18 + pos) * XS_STRIDE + cq * 4] = h4;
        }
    }
    __syncthreads();   // barrier 1: xs ready (all waves read all of it)

    // ---- trunk K-loop: 18 s-steps, barrier-free, reg-double-buffered B ----
    f32x4 acc[2][8];
    #pragma unroll
    for (int km = 0; km < 2; ++km)
        #pragma unroll
        for (int l = 0; l < 8; ++l)
            acc[km][l] = (f32x4){0.f, 0.f, 0.f, 0.f};

    for (int s = 0; s < 18; s += 2) {
        {   // prefetch s+1 -> bB (always exists: s+1 <= 17)
            const char* g1 = gW + (size_t)(s + 1) * BS_BYTES;
            #pragma unroll
            for (int l = 0; l < 8; ++l)
                bB[l] = *(const fp16x8*)(g1 + (size_t)l * 1024);
        }
        TRUNK_STEP(s, bA);
        if (s + 2 < 18) {   // prefetch s+2 -> bA
            const char* g2 = gW + (size_t)(s + 2) * BS_BYTES;
            #pragma unroll
            for (int l = 0; l < 8; ++l)
                bA[l] = *(const fp16x8*)(g2 + (size_t)l * 1024);
        }
        TRUNK_STEP(s + 1, bB);
    }

    __syncthreads();   // barrier 2: trunk done, xs dead, arena reusable

    // ---- fused 1x1 heads: per-wave k-slice GEMM feat[32][128] x w2[128][48] ----
    _Float16* fh = (_Float16*)(smem + wave * FB_PER_WAVE);
    _Float16* fl = fh + 32 * 36;

    f32x4 acc2[2][3];
    #pragma unroll
    for (int km = 0; km < 2; ++km)
        #pragma unroll
        for (int ns = 0; ns < 3; ++ns)
            acc2[km][ns] = (f32x4){0.f, 0.f, 0.f, 0.f};

    for (int sub = 0; sub < 4; ++sub) {       // 4 k-chunks of 32 within the slice
        // dump this wave's 32-channel slice of feat (bias+relu, fp16 hi/lo)
        #pragma unroll
        for (int lh = 0; lh < 2; ++lh) {
            int l = sub * 2 + lh;
            float bias = b_base[n0 + l * 16 + lr];
            #pragma unroll
            for (int km = 0; km < 2; ++km) {
                #pragma unroll
                for (int r = 0; r < 4; ++r) {
                    float v = acc[km][l][r] + bias;
                    v = v > 0.f ? v : 0.f;
                    _Float16 h = (_Float16)v;
                    int row = km * 16 + q * 4 + r;
                    int col = lh * 16 + lr;
                    fh[row * 36 + col] = h;
                    fl[row * 36 + col] = (_Float16)(v - (float)h);
                }
            }
        }
        asm volatile("s_waitcnt lgkmcnt(0)" ::: "memory");  // wave-local RAW fence

        // A-frags: feat rows, k-local = q*8..q*8+7 (8-byte aligned -> 2x b64)
        fp16x8 fah[2], fal[2];
        #pragma unroll
        for (int km = 0; km < 2; ++km) {
            int off = (km * 16 + lr) * 36 + q * 8;
            union { fp16x8 v8; fp16x4 v4[2]; } uh, ul;
            uh.v4[0] = *(const fp16x4*)&fh[off];
            uh.v4[1] = *(const fp16x4*)&fh[off + 4];
            ul.v4[0] = *(const fp16x4*)&fl[off];
            ul.v4[1] = *(const fp16x4*)&fl[off + 4];
            fah[km] = uh.v8;
            fal[km] = ul.v8;
        }

        const int kg = n0 + sub * 32 + q * 8;   // global k for B frags
        // ns = 0 (contains the 9 score cols): 3-pass hi/lo
        {
            int eo = (0 * 16 + lr) * 512 + kg;
            fp16x8 wh = *(const fp16x8*)&bt2_hi[eo];
            fp16x8 wl = *(const fp16x8*)&bt2_lo[eo];
            #pragma unroll
            for (int km = 0; km < 2; ++km)
                acc2[km][0] = __builtin_amdgcn_mfma_f32_16x16x32_f16(fah[km], wh, acc2[km][0], 0, 0, 0);
            #pragma unroll
            for (int km = 0; km < 2; ++km)
                acc2[km][0] = __builtin_amdgcn_mfma_f32_16x16x32_f16(fah[km], wl, acc2[km][0], 0, 0, 0);
            #pragma unroll
            for (int km = 0; km < 2; ++km)
                acc2[km][0] = __builtin_amdgcn_mfma_f32_16x16x32_f16(fal[km], wh, acc2[km][0], 0, 0, 0);
        }
        // ns = 1,2 (pure delta cols): 2-pass (w fp16 single, feat hi+lo)
        #pragma unroll
        for (int ns = 1; ns < 3; ++ns) {
            int eo = (ns * 16 + lr) * 512 + kg;
            fp16x8 wh = *(const fp16x8*)&bt2_hi[eo];
            #pragma unroll
            for (int km = 0; km < 2; ++km)
                acc2[km][ns] = __builtin_amdgcn_mfma_f32_16x16x32_f16(fah[km], wh, acc2[km][ns], 0, 0, 0);
            #pragma unroll
            for (int km = 0; km < 2; ++km)
                acc2[km][ns] = __builtin_amdgcn_mfma_f32_16x16x32_f16(fal[km], wh, acc2[km][ns], 0, 0, 0);
        }
    }

    __syncthreads();   // barrier 3: all fbuf reads done, arena reusable

    // ---- parallel cross-wave partials: wave w -> zb slice w [32][50] ----
    {
        float* zw = zb + wave * ZB_SLICE;
        #pragma unroll
        for (int km = 0; km < 2; ++km)
            #pragma unroll
            for (int ns = 0; ns < 3; ++ns)
                #pragma unroll
                for (int r = 0; r < 4; ++r) {
                    int row = km * 16 + q * 4 + r;
                    int col = ns * 16 + lr;
                    zw[row * 50 + col] = acc2[km][ns][r];
                }
    }
    __syncthreads();   // barrier 4: partials visible

    // ---- epilogue: sum k-slices (fixed order == old staged reduction),
    //      sigmoid, threshold mask, store ----
    for (int i = tid; i < 32 * 45; i += 256) {
        int m = i / 45;
        int o = i - m * 45;
        int e0 = m * 50 + o;
        float z = ((zb[e0] + zb[ZB_SLICE + e0]) + zb[2 * ZB_SLICE + e0]) + zb[3 * ZB_SLICE + e0];
        float v;
        if (o < 9) {
            v = 1.f / (1.f + expf(-(z + b_cls[o])));
        } else {
            int d = o - 9;
            int a = d >> 2;
            int ea = m * 50 + a;
            float za = ((zb[ea] + zb[ZB_SLICE + ea]) + zb[2 * ZB_SLICE + ea]) + zb[3 * ZB_SLICE + ea];
            float s = 1.f / (1.f + expf(-(za + b_cls[a])));
            v = (s > 0.7f) ? (z + b_reg[d]) : 0.f;
        }
        int mh = m >> 4, mw = m & 15;
        out[(((b * 256 + h0 + mh) * 256) + w0 + mw) * 45 + o] = v;
    }
}

// ---------------------------------------------------------------------------
extern "C" void kernel_launch(void* const* d_in, const int* in_sizes, int n_in,
                              void* d_out, int out_size, void* d_ws, size_t ws_size,
                              hipStream_t stream)
{
    const float* x      = (const float*)d_in[0];
    const float* w_base = (const float*)d_in[1];
    const float* b_base = (const float*)d_in[2];
    const float* w_cls  = (const float*)d_in[3];
    const float* b_cls  = (const float*)d_in[4];
    const float* w_reg  = (const float*)d_in[5];
    const float* b_reg  = (const float*)d_in[6];
    float* out = (float*)d_out;

    _Float16* btI    = (_Float16*)d_ws;
    _Float16* bt2_hi = btI + BT_ELEMS;
    _Float16* bt2_lo = bt2_hi + BT2_ELEMS;

    rpn_prep<<<(BT_ELEMS + BT2_ELEMS + 255) / 256, 256, 0, stream>>>(
        w_base, w_cls, w_reg, btI, bt2_hi, bt2_lo);
    rpn_main<<<8192, 256, 0, stream>>>(
        x, b_base, b_cls, b_reg, btI, bt2_hi, bt2_lo, out);
}

// Round 7
// 344.913 us; speedup vs baseline: 1.1579x; 1.0456x over previous
//
#include <hip/hip_runtime.h>
#include <hip/hip_bf16.h>
#include <math.h>

// ---------------------------------------------------------------------------
// RPN fused kernel for MI355X (gfx950)
//   trunk : 3x3 conv 64->512 + bias + relu   (fp16 single-pass MFMA)
//   heads : 1x1 conv 512->9 (sigmoid) and 512->36 (linear), deltas masked by
//           score > 0.7, output [B,H,W,45] fp32
// Round 11 (resubmit; R5 bench lost to GPU-acquisition timeout):
//   latency trims on the MFMA feed chains. R10 (-12%) confirmed the
//   stall-reduction theory. Counter re-analysis: VALUBusy ~= MfmaUtil+2% in
//   all rounds => VALU includes MFMA issue, scalar VALU only ~2%. b64/b128
//   sweep-minimum math shows head/trunk LDS READS are conflict-free; residual
//   2.59M conflicts (1.4% cyc) = scalar b16 dump writes - not a lever.
//   This round (FP order bitwise-identical, arena unchanged 25600 B):
//   1) trunk A-frag double-buffer (ahA/ahB): ds_read for s+1 issues before
//      MFMA cluster of s; s-loop fully unrolled (static offsets).
//   2) head: bt2 weight loads hoisted BEFORE the lgkmcnt(0) drain (L2
//      latency overlaps the LDS drain instead of following it).
//   3) setprio(1) around head MFMA clusters (parity with trunk).
//   4) x-stage HBM loads issue before the bA L2 prefetch (longest first).
// ---------------------------------------------------------------------------

typedef _Float16 fp16x8 __attribute__((ext_vector_type(8)));
typedef _Float16 fp16x4 __attribute__((ext_vector_type(4)));
typedef float    f32x4  __attribute__((ext_vector_type(4)));

#define BT_ELEMS  (18 * 32 * 64 * 8)    // 294912 trunk weights fp16
#define BT2_ELEMS (48 * 512)            // head weights, [o][k] k-major
#define BS_BYTES  32768                 // trunk weight bytes per s-step

// ---------------------------------------------------------------------------
// prep: trunk weights -> fp16 bt[s][j=wv*8+l][lane][8]; head weights hi/lo.
// (unchanged)
// ---------------------------------------------------------------------------
__global__ __launch_bounds__(256) void rpn_prep(
    const float* __restrict__ wb,   // [3][3][64][512]
    const float* __restrict__ wc,   // [512][9]
    const float* __restrict__ wr,   // [512][36]
    _Float16* __restrict__ btI,
    _Float16* __restrict__ bt2_hi, _Float16* __restrict__ bt2_lo)
{
    int t = blockIdx.x * 256 + threadIdx.x;
    if (t < BT_ELEMS) {
        int e    = t & 7;
        int lane = (t >> 3) & 63;
        int j    = (t >> 9) & 31;
        int s    = t >> 14;              // 0..17
        int wv   = j >> 3, l = j & 7;
        int lr   = lane & 15, q = lane >> 4;
        int n    = wv * 128 + l * 16 + lr;
        int k    = s * 32 + q * 8 + e;   // 0..575
        int tap  = k >> 6, c = k & 63;   // k = (ky*3+kx)*64 + c
        btI[t] = (_Float16)wb[(tap * 64 + c) * 512 + n];
    } else if (t < BT_ELEMS + BT2_ELEMS) {
        int jj = t - BT_ELEMS;
        int k = jj & 511;
        int o = jj >> 9;                 // 0..47
        float v = 0.f;
        if (o < 9)       v = wc[k * 9 + o];
        else if (o < 45) v = wr[k * 36 + (o - 9)];
        _Float16 h = (_Float16)v;
        bt2_hi[jj] = h;
        bt2_lo[jj] = (_Float16)(v - (float)h);
    }
}

// ---------------------------------------------------------------------------
// main fused kernel: 8192 workgroups x 256 threads
//   tile = 32 output positions (2 h-rows x 16 w) x 512 channels
//   wave w owns channel slice [128w, 128w+128); acc[2][8] = 64 AGPR
// LDS arena (25600 B):
//   trunk phase: xs_hi [4][18][76] fp16 @ 0   (10944 B; shared by all waves)
//   head  phase (after barrier 2, xs dead):
//     fbuf per wave @ w*4608 (fh [32][36] fp16, fl +2304 B)   [0, 18432)
//   reduction (after barrier 3, fbuf dead):
//     zbuf4 [4][32][50] f32 @ 0   (25600 B; wave w owns slice w)
// ---------------------------------------------------------------------------
#define XS_STRIDE   76
#define FB_PER_WAVE 4608
#define ZB_SLICE    1600                 // floats per wave slice (32*50)
#define ARENA_BYTES 25600

// A-frag ds_read pair for s-step S into AH[2]
#define LOAD_AH(S, AH)                                                        \
    {                                                                         \
        const int tap_ = (S) >> 1;                                            \
        const int ky_  = tap_ / 3;                                            \
        const int kx_  = tap_ - ky_ * 3;                                      \
        const int c0_  = ((S) & 1) * 32 + q * 8;                              \
        _Pragma("unroll")                                                     \
        for (int km = 0; km < 2; ++km)                                        \
            AH[km] = *(const fp16x8*)&xs_hi[((km + ky_) * 18 + lr + kx_) * XS_STRIDE + c0_]; \
    }

// 16 MFMAs from registers
#define MFMA_STEP(AH, BREG)                                                   \
    {                                                                         \
        __builtin_amdgcn_s_setprio(1);                                        \
        _Pragma("unroll")                                                     \
        for (int l = 0; l < 8; ++l) {                                         \
            acc[0][l] = __builtin_amdgcn_mfma_f32_16x16x32_f16(AH[0], BREG[l], acc[0][l], 0, 0, 0); \
            acc[1][l] = __builtin_amdgcn_mfma_f32_16x16x32_f16(AH[1], BREG[l], acc[1][l], 0, 0, 0); \
        }                                                                     \
        __builtin_amdgcn_s_setprio(0);                                        \
    }

__global__ __launch_bounds__(256, 3) void rpn_main(
    const float* __restrict__ x,        // [4][256][256][64]
    const float* __restrict__ b_base,   // [512]
    const float* __restrict__ b_cls,    // [9]
    const float* __restrict__ b_reg,    // [36]
    const _Float16* __restrict__ btI,
    const _Float16* __restrict__ bt2_hi, const _Float16* __restrict__ bt2_lo,
    float* __restrict__ out)            // [4][256][256][45]
{
    __shared__ char smem[ARENA_BYTES];
    _Float16* xs_hi = (_Float16*)smem;          // trunk phase only
    float*    zb    = (float*)smem;             // reduction phase only

    const int tid  = threadIdx.x;
    const int wave = tid >> 6;
    const int lane = tid & 63;
    const int q    = lane >> 4;     // 0..3
    const int lr   = lane & 15;     // 0..15
    const int n0   = wave * 128;    // wave's channel-slice base

    const int wg  = blockIdx.x;
    const int b   = wg >> 11;           // 2048 tiles per image
    const int rem = wg & 2047;
    const int h0  = (rem >> 4) * 2;     // 2 h-rows per tile
    const int w0  = (rem & 15) * 16;    // 16 w-positions per tile

    // ---- stage x patch FIRST (HBM, longest latency): 4 rows x 18 pos x 64 ch
    //      as fp16 (shared, 4x reuse across waves) ----
    for (int i = 0; i < 5; ++i) {
        int flat = tid + i * 256;
        if (flat < 4 * 18 * 16) {
            int cq  = flat & 15;          // channel quad
            int rp  = flat >> 4;          // 0..71
            int row = rp / 18;
            int pos = rp - row * 18;
            int hh  = h0 - 1 + row;
            int ww  = w0 - 1 + pos;
            fp16x4 h4;
            if (hh >= 0 && hh < 256 && ww >= 0 && ww < 256) {
                const float4 v = *(const float4*)&x[(((b * 256 + hh) * 256 + ww) * 64 + cq * 4)];
                h4[0] = (_Float16)v.x; h4[1] = (_Float16)v.y;
                h4[2] = (_Float16)v.z; h4[3] = (_Float16)v.w;
            } else {
                #pragma unroll
                for (int j = 0; j < 4; ++j) h4[j] = (_Float16)0.f;
            }
            *(fp16x4*)&xs_hi[(row * 18 + pos) * XS_STRIDE + cq * 4] = h4;
        }
    }

    // wave's B-frag base in global: frag (s,wave,l,lane) at
    //   s*32768 + wave*8192 + l*1024 + lane*16 bytes
    const char* gW = (const char*)btI + wave * 8192 + lane * 16;

    // ---- issue B(s=0) into registers (L2; latency hides under barrier 1) ----
    fp16x8 bA[8], bB[8];
    #pragma unroll
    for (int l = 0; l < 8; ++l)
        bA[l] = *(const fp16x8*)(gW + (size_t)l * 1024);

    __syncthreads();   // barrier 1: xs ready (all waves read all of it)

    // ---- trunk K-loop: 18 s-steps, barrier-free, reg-double-buffered B AND A
    //      (ah(s+1) ds_reads issue before MFMA(s); fully unrolled) ----
    f32x4 acc[2][8];
    #pragma unroll
    for (int km = 0; km < 2; ++km)
        #pragma unroll
        for (int l = 0; l < 8; ++l)
            acc[km][l] = (f32x4){0.f, 0.f, 0.f, 0.f};

    fp16x8 ahA[2], ahB[2];
    LOAD_AH(0, ahA);

    #pragma unroll
    for (int s = 0; s < 18; s += 2) {
        {   // prefetch B(s+1) -> bB (always exists: s+1 <= 17)
            const char* g1 = gW + (size_t)(s + 1) * BS_BYTES;
            #pragma unroll
            for (int l = 0; l < 8; ++l)
                bB[l] = *(const fp16x8*)(g1 + (size_t)l * 1024);
        }
        LOAD_AH(s + 1, ahB);         // A(s+1) reads overlap MFMA(s)
        MFMA_STEP(ahA, bA);
        if (s + 2 < 18) {            // prefetch B(s+2) -> bA, A(s+2) -> ahA
            const char* g2 = gW + (size_t)(s + 2) * BS_BYTES;
            #pragma unroll
            for (int l = 0; l < 8; ++l)
                bA[l] = *(const fp16x8*)(g2 + (size_t)l * 1024);
            LOAD_AH(s + 2, ahA);
        }
        MFMA_STEP(ahB, bB);
    }

    __syncthreads();   // barrier 2: trunk done, xs dead, arena reusable

    // ---- fused 1x1 heads: per-wave k-slice GEMM feat[32][128] x w2[128][48] ----
    _Float16* fh = (_Float16*)(smem + wave * FB_PER_WAVE);
    _Float16* fl = fh + 32 * 36;

    f32x4 acc2[2][3];
    #pragma unroll
    for (int km = 0; km < 2; ++km)
        #pragma unroll
        for (int ns = 0; ns < 3; ++ns)
            acc2[km][ns] = (f32x4){0.f, 0.f, 0.f, 0.f};

    #pragma unroll
    for (int sub = 0; sub < 4; ++sub) {       // 4 k-chunks of 32 within the slice
        // dump this wave's 32-channel slice of feat (bias+relu, fp16 hi/lo)
        #pragma unroll
        for (int lh = 0; lh < 2; ++lh) {
            int l = sub * 2 + lh;
            float bias = b_base[n0 + l * 16 + lr];
            #pragma unroll
            for (int km = 0; km < 2; ++km) {
                #pragma unroll
                for (int r = 0; r < 4; ++r) {
                    float v = acc[km][l][r] + bias;
                    v = v > 0.f ? v : 0.f;
                    _Float16 h = (_Float16)v;
                    int row = km * 16 + q * 4 + r;
                    int col = lh * 16 + lr;
                    fh[row * 36 + col] = h;
                    fl[row * 36 + col] = (_Float16)(v - (float)h);
                }
            }
        }

        // hoist head-weight loads BEFORE the drain: L2 latency overlaps it
        const int kg = n0 + sub * 32 + q * 8;   // global k for B frags
        fp16x8 wh0 = *(const fp16x8*)&bt2_hi[(0 * 16 + lr) * 512 + kg];
        fp16x8 wl0 = *(const fp16x8*)&bt2_lo[(0 * 16 + lr) * 512 + kg];
        fp16x8 wh1 = *(const fp16x8*)&bt2_hi[(1 * 16 + lr) * 512 + kg];
        fp16x8 wh2 = *(const fp16x8*)&bt2_hi[(2 * 16 + lr) * 512 + kg];

        asm volatile("s_waitcnt lgkmcnt(0)" ::: "memory");  // wave-local RAW fence

        // A-frags: feat rows, k-local = q*8..q*8+7 (8-byte aligned -> 2x b64)
        fp16x8 fah[2], fal[2];
        #pragma unroll
        for (int km = 0; km < 2; ++km) {
            int off = (km * 16 + lr) * 36 + q * 8;
            union { fp16x8 v8; fp16x4 v4[2]; } uh, ul;
            uh.v4[0] = *(const fp16x4*)&fh[off];
            uh.v4[1] = *(const fp16x4*)&fh[off + 4];
            ul.v4[0] = *(const fp16x4*)&fl[off];
            ul.v4[1] = *(const fp16x4*)&fl[off + 4];
            fah[km] = uh.v8;
            fal[km] = ul.v8;
        }

        __builtin_amdgcn_s_setprio(1);
        // ns = 0 (contains the 9 score cols): 3-pass hi/lo
        #pragma unroll
        for (int km = 0; km < 2; ++km)
            acc2[km][0] = __builtin_amdgcn_mfma_f32_16x16x32_f16(fah[km], wh0, acc2[km][0], 0, 0, 0);
        #pragma unroll
        for (int km = 0; km < 2; ++km)
            acc2[km][0] = __builtin_amdgcn_mfma_f32_16x16x32_f16(fah[km], wl0, acc2[km][0], 0, 0, 0);
        #pragma unroll
        for (int km = 0; km < 2; ++km)
            acc2[km][0] = __builtin_amdgcn_mfma_f32_16x16x32_f16(fal[km], wh0, acc2[km][0], 0, 0, 0);
        // ns = 1,2 (pure delta cols): 2-pass (w fp16 single, feat hi+lo)
        #pragma unroll
        for (int km = 0; km < 2; ++km)
            acc2[km][1] = __builtin_amdgcn_mfma_f32_16x16x32_f16(fah[km], wh1, acc2[km][1], 0, 0, 0);
        #pragma unroll
        for (int km = 0; km < 2; ++km)
            acc2[km][1] = __builtin_amdgcn_mfma_f32_16x16x32_f16(fal[km], wh1, acc2[km][1], 0, 0, 0);
        #pragma unroll
        for (int km = 0; km < 2; ++km)
            acc2[km][2] = __builtin_amdgcn_mfma_f32_16x16x32_f16(fah[km], wh2, acc2[km][2], 0, 0, 0);
        #pragma unroll
        for (int km = 0; km < 2; ++km)
            acc2[km][2] = __builtin_amdgcn_mfma_f32_16x16x32_f16(fal[km], wh2, acc2[km][2], 0, 0, 0);
        __builtin_amdgcn_s_setprio(0);
    }

    __syncthreads();   // barrier 3: all fbuf reads done, arena reusable

    // ---- parallel cross-wave partials: wave w -> zb slice w [32][50] ----
    {
        float* zw = zb + wave * ZB_SLICE;
        #pragma unroll
        for (int km = 0; km < 2; ++km)
            #pragma unroll
            for (int ns = 0; ns < 3; ++ns)
                #pragma unroll
                for (int r = 0; r < 4; ++r) {
                    int row = km * 16 + q * 4 + r;
                    int col = ns * 16 + lr;
                    zw[row * 50 + col] = acc2[km][ns][r];
                }
    }
    __syncthreads();   // barrier 4: partials visible

    // ---- epilogue: sum k-slices (fixed order == old staged reduction),
    //      sigmoid, threshold mask, store ----
    for (int i = tid; i < 32 * 45; i += 256) {
        int m = i / 45;
        int o = i - m * 45;
        int e0 = m * 50 + o;
        float z = ((zb[e0] + zb[ZB_SLICE + e0]) + zb[2 * ZB_SLICE + e0]) + zb[3 * ZB_SLICE + e0];
        float v;
        if (o < 9) {
            v = 1.f / (1.f + expf(-(z + b_cls[o])));
        } else {
            int d = o - 9;
            int a = d >> 2;
            int ea = m * 50 + a;
            float za = ((zb[ea] + zb[ZB_SLICE + ea]) + zb[2 * ZB_SLICE + ea]) + zb[3 * ZB_SLICE + ea];
            float s = 1.f / (1.f + expf(-(za + b_cls[a])));
            v = (s > 0.7f) ? (z + b_reg[d]) : 0.f;
        }
        int mh = m >> 4, mw = m & 15;
        out[(((b * 256 + h0 + mh) * 256) + w0 + mw) * 45 + o] = v;
    }
}

// ---------------------------------------------------------------------------
extern "C" void kernel_launch(void* const* d_in, const int* in_sizes, int n_in,
                              void* d_out, int out_size, void* d_ws, size_t ws_size,
                              hipStream_t stream)
{
    const float* x      = (const float*)d_in[0];
    const float* w_base = (const float*)d_in[1];
    const float* b_base = (const float*)d_in[2];
    const float* w_cls  = (const float*)d_in[3];
    const float* b_cls  = (const float*)d_in[4];
    const float* w_reg  = (const float*)d_in[5];
    const float* b_reg  = (const float*)d_in[6];
    float* out = (float*)d_out;

    _Float16* btI    = (_Float16*)d_ws;
    _Float16* bt2_hi = btI + BT_ELEMS;
    _Float16* bt2_lo = bt2_hi + BT2_ELEMS;

    rpn_prep<<<(BT_ELEMS + BT2_ELEMS + 255) / 256, 256, 0, stream>>>(
        w_base, w_cls, w_reg, btI, bt2_hi, bt2_lo);
    rpn_main<<<8192, 256, 0, stream>>>(
        x, b_base, b_cls, b_reg, btI, bt2_hi, bt2_lo, out);
}

// Round 9
// 342.790 us; speedup vs baseline: 1.1651x; 1.0062x over previous
//
#include <hip/hip_runtime.h>
#include <hip/hip_bf16.h>
#include <math.h>

// ---------------------------------------------------------------------------
// RPN fused kernel for MI355X (gfx950)
//   trunk : 3x3 conv 64->512 + bias + relu   (fp16 single-pass MFMA)
//   heads : 1x1 conv 512->9 (sigmoid) and 512->36 (linear), deltas masked by
//           score > 0.7, output [B,H,W,45] fp32
// Round 12 (resubmit; R7 bench lost to container failure, pre-dispatch):
//   de-barrier trunk->head + one-sub-ahead head weight prefetch.
//   R11 (-3%) showed per-step feed trims saturating. Remaining serialization:
//   barrier 2 existed ONLY because fbuf aliased xs in LDS -- the head phase
//   is wave-local until the zb reduction. Fix: fbuf gets its own region
//   (arena 25600 -> 29376 B; zb overlay still safe after barrier 3). Waves
//   now run trunk-tail/head-dump/weight-load phases desynchronized ->
//   inter-wave pipe diversity (MFMA + LDS + VMEM mix on each SIMD).
//   Head weights rotate cw*/nw*: sub s+1's L2 loads issue during sub s's
//   dump (covered ~600 cyc instead of ~150).
//   FP order bitwise-identical to R11 (absmax canary 0.00390625).
// ---------------------------------------------------------------------------

typedef _Float16 fp16x8 __attribute__((ext_vector_type(8)));
typedef _Float16 fp16x4 __attribute__((ext_vector_type(4)));
typedef float    f32x4  __attribute__((ext_vector_type(4)));

#define BT_ELEMS  (18 * 32 * 64 * 8)    // 294912 trunk weights fp16
#define BT2_ELEMS (48 * 512)            // head weights, [o][k] k-major
#define BS_BYTES  32768                 // trunk weight bytes per s-step

// ---------------------------------------------------------------------------
// prep: trunk weights -> fp16 bt[s][j=wv*8+l][lane][8]; head weights hi/lo.
// (unchanged)
// ---------------------------------------------------------------------------
__global__ __launch_bounds__(256) void rpn_prep(
    const float* __restrict__ wb,   // [3][3][64][512]
    const float* __restrict__ wc,   // [512][9]
    const float* __restrict__ wr,   // [512][36]
    _Float16* __restrict__ btI,
    _Float16* __restrict__ bt2_hi, _Float16* __restrict__ bt2_lo)
{
    int t = blockIdx.x * 256 + threadIdx.x;
    if (t < BT_ELEMS) {
        int e    = t & 7;
        int lane = (t >> 3) & 63;
        int j    = (t >> 9) & 31;
        int s    = t >> 14;              // 0..17
        int wv   = j >> 3, l = j & 7;
        int lr   = lane & 15, q = lane >> 4;
        int n    = wv * 128 + l * 16 + lr;
        int k    = s * 32 + q * 8 + e;   // 0..575
        int tap  = k >> 6, c = k & 63;   // k = (ky*3+kx)*64 + c
        btI[t] = (_Float16)wb[(tap * 64 + c) * 512 + n];
    } else if (t < BT_ELEMS + BT2_ELEMS) {
        int jj = t - BT_ELEMS;
        int k = jj & 511;
        int o = jj >> 9;                 // 0..47
        float v = 0.f;
        if (o < 9)       v = wc[k * 9 + o];
        else if (o < 45) v = wr[k * 36 + (o - 9)];
        _Float16 h = (_Float16)v;
        bt2_hi[jj] = h;
        bt2_lo[jj] = (_Float16)(v - (float)h);
    }
}

// ---------------------------------------------------------------------------
// main fused kernel: 8192 workgroups x 256 threads
//   tile = 32 output positions (2 h-rows x 16 w) x 512 channels
//   wave w owns channel slice [128w, 128w+128); acc[2][8] = 64 AGPR
// LDS arena (29376 B):
//   xs_hi [4][18][76] fp16 @ 0                     (10944 B; trunk, shared)
//   fbuf per wave @ 10944 + w*4608                 (18432 B; head, wave-private)
//   zb [4][32][50] f32 @ 0 overlay                 (25600 B; after barrier 3,
//                                                   xs and fbuf both dead)
//   NO barrier between trunk and head: fbuf is disjoint from xs, and the
//   head phase is wave-local until the zb reduction.
// ---------------------------------------------------------------------------
#define XS_STRIDE   76
#define FB_OFF      10944
#define FB_PER_WAVE 4608
#define ZB_SLICE    1600                 // floats per wave slice (32*50)
#define ARENA_BYTES 29376

// A-frag ds_read pair for s-step S into AH[2]
#define LOAD_AH(S, AH)                                                        \
    {                                                                         \
        const int tap_ = (S) >> 1;                                            \
        const int ky_  = tap_ / 3;                                            \
        const int kx_  = tap_ - ky_ * 3;                                      \
        const int c0_  = ((S) & 1) * 32 + q * 8;                              \
        _Pragma("unroll")                                                     \
        for (int km = 0; km < 2; ++km)                                        \
            AH[km] = *(const fp16x8*)&xs_hi[((km + ky_) * 18 + lr + kx_) * XS_STRIDE + c0_]; \
    }

// 16 MFMAs from registers
#define MFMA_STEP(AH, BREG)                                                   \
    {                                                                         \
        __builtin_amdgcn_s_setprio(1);                                        \
        _Pragma("unroll")                                                     \
        for (int l = 0; l < 8; ++l) {                                         \
            acc[0][l] = __builtin_amdgcn_mfma_f32_16x16x32_f16(AH[0], BREG[l], acc[0][l], 0, 0, 0); \
            acc[1][l] = __builtin_amdgcn_mfma_f32_16x16x32_f16(AH[1], BREG[l], acc[1][l], 0, 0, 0); \
        }                                                                     \
        __builtin_amdgcn_s_setprio(0);                                        \
    }

__global__ __launch_bounds__(256, 3) void rpn_main(
    const float* __restrict__ x,        // [4][256][256][64]
    const float* __restrict__ b_base,   // [512]
    const float* __restrict__ b_cls,    // [9]
    const float* __restrict__ b_reg,    // [36]
    const _Float16* __restrict__ btI,
    const _Float16* __restrict__ bt2_hi, const _Float16* __restrict__ bt2_lo,
    float* __restrict__ out)            // [4][256][256][45]
{
    __shared__ char smem[ARENA_BYTES];
    _Float16* xs_hi = (_Float16*)smem;          // trunk phase only
    float*    zb    = (float*)smem;             // reduction phase only

    const int tid  = threadIdx.x;
    const int wave = tid >> 6;
    const int lane = tid & 63;
    const int q    = lane >> 4;     // 0..3
    const int lr   = lane & 15;     // 0..15
    const int n0   = wave * 128;    // wave's channel-slice base

    const int wg  = blockIdx.x;
    const int b   = wg >> 11;           // 2048 tiles per image
    const int rem = wg & 2047;
    const int h0  = (rem >> 4) * 2;     // 2 h-rows per tile
    const int w0  = (rem & 15) * 16;    // 16 w-positions per tile

    // ---- stage x patch FIRST (HBM, longest latency): 4 rows x 18 pos x 64 ch
    //      as fp16 (shared, 4x reuse across waves) ----
    for (int i = 0; i < 5; ++i) {
        int flat = tid + i * 256;
        if (flat < 4 * 18 * 16) {
            int cq  = flat & 15;          // channel quad
            int rp  = flat >> 4;          // 0..71
            int row = rp / 18;
            int pos = rp - row * 18;
            int hh  = h0 - 1 + row;
            int ww  = w0 - 1 + pos;
            fp16x4 h4;
            if (hh >= 0 && hh < 256 && ww >= 0 && ww < 256) {
                const float4 v = *(const float4*)&x[(((b * 256 + hh) * 256 + ww) * 64 + cq * 4)];
                h4[0] = (_Float16)v.x; h4[1] = (_Float16)v.y;
                h4[2] = (_Float16)v.z; h4[3] = (_Float16)v.w;
            } else {
                #pragma unroll
                for (int j = 0; j < 4; ++j) h4[j] = (_Float16)0.f;
            }
            *(fp16x4*)&xs_hi[(row * 18 + pos) * XS_STRIDE + cq * 4] = h4;
        }
    }

    // wave's B-frag base in global: frag (s,wave,l,lane) at
    //   s*32768 + wave*8192 + l*1024 + lane*16 bytes
    const char* gW = (const char*)btI + wave * 8192 + lane * 16;

    // ---- issue B(s=0) into registers (L2; latency hides under barrier 1) ----
    fp16x8 bA[8], bB[8];
    #pragma unroll
    for (int l = 0; l < 8; ++l)
        bA[l] = *(const fp16x8*)(gW + (size_t)l * 1024);

    __syncthreads();   // barrier 1: xs ready (all waves read all of it)

    // ---- trunk K-loop: 18 s-steps, barrier-free, reg-double-buffered B AND A
    //      (ah(s+1) ds_reads issue before MFMA(s); fully unrolled) ----
    f32x4 acc[2][8];
    #pragma unroll
    for (int km = 0; km < 2; ++km)
        #pragma unroll
        for (int l = 0; l < 8; ++l)
            acc[km][l] = (f32x4){0.f, 0.f, 0.f, 0.f};

    fp16x8 ahA[2], ahB[2];
    LOAD_AH(0, ahA);

    #pragma unroll
    for (int s = 0; s < 18; s += 2) {
        {   // prefetch B(s+1) -> bB (always exists: s+1 <= 17)
            const char* g1 = gW + (size_t)(s + 1) * BS_BYTES;
            #pragma unroll
            for (int l = 0; l < 8; ++l)
                bB[l] = *(const fp16x8*)(g1 + (size_t)l * 1024);
        }
        LOAD_AH(s + 1, ahB);         // A(s+1) reads overlap MFMA(s)
        MFMA_STEP(ahA, bA);
        if (s + 2 < 18) {            // prefetch B(s+2) -> bA, A(s+2) -> ahA
            const char* g2 = gW + (size_t)(s + 2) * BS_BYTES;
            #pragma unroll
            for (int l = 0; l < 8; ++l)
                bA[l] = *(const fp16x8*)(g2 + (size_t)l * 1024);
            LOAD_AH(s + 2, ahA);
        }
        MFMA_STEP(ahB, bB);
    }

    // NO barrier here (was barrier 2): fbuf region is disjoint from xs and
    // wave-private; head phase has no cross-wave dependency until zb.

    // ---- fused 1x1 heads: per-wave k-slice GEMM feat[32][128] x w2[128][48] ----
    _Float16* fh = (_Float16*)(smem + FB_OFF + wave * FB_PER_WAVE);
    _Float16* fl = fh + 32 * 36;

    f32x4 acc2[2][3];
    #pragma unroll
    for (int km = 0; km < 2; ++km)
        #pragma unroll
        for (int ns = 0; ns < 3; ++ns)
            acc2[km][ns] = (f32x4){0.f, 0.f, 0.f, 0.f};

    // preload sub-0 head weights (L2)
    fp16x8 cwh0, cwl0, cwh1, cwh2;
    {
        const int kg0 = n0 + q * 8;
        cwh0 = *(const fp16x8*)&bt2_hi[(0 * 16 + lr) * 512 + kg0];
        cwl0 = *(const fp16x8*)&bt2_lo[(0 * 16 + lr) * 512 + kg0];
        cwh1 = *(const fp16x8*)&bt2_hi[(1 * 16 + lr) * 512 + kg0];
        cwh2 = *(const fp16x8*)&bt2_hi[(2 * 16 + lr) * 512 + kg0];
    }

    #pragma unroll
    for (int sub = 0; sub < 4; ++sub) {       // 4 k-chunks of 32 within the slice
        // dump this wave's 32-channel slice of feat (bias+relu, fp16 hi/lo)
        #pragma unroll
        for (int lh = 0; lh < 2; ++lh) {
            int l = sub * 2 + lh;
            float bias = b_base[n0 + l * 16 + lr];
            #pragma unroll
            for (int km = 0; km < 2; ++km) {
                #pragma unroll
                for (int r = 0; r < 4; ++r) {
                    float v = acc[km][l][r] + bias;
                    v = v > 0.f ? v : 0.f;
                    _Float16 h = (_Float16)v;
                    int row = km * 16 + q * 4 + r;
                    int col = lh * 16 + lr;
                    fh[row * 36 + col] = h;
                    fl[row * 36 + col] = (_Float16)(v - (float)h);
                }
            }
        }

        // prefetch NEXT sub's head weights (used ~600 cyc later)
        fp16x8 nwh0, nwl0, nwh1, nwh2;
        if (sub < 3) {
            const int kgn = n0 + (sub + 1) * 32 + q * 8;
            nwh0 = *(const fp16x8*)&bt2_hi[(0 * 16 + lr) * 512 + kgn];
            nwl0 = *(const fp16x8*)&bt2_lo[(0 * 16 + lr) * 512 + kgn];
            nwh1 = *(const fp16x8*)&bt2_hi[(1 * 16 + lr) * 512 + kgn];
            nwh2 = *(const fp16x8*)&bt2_hi[(2 * 16 + lr) * 512 + kgn];
        }

        asm volatile("s_waitcnt lgkmcnt(0)" ::: "memory");  // wave-local RAW fence

        // A-frags: feat rows, k-local = q*8..q*8+7 (8-byte aligned -> 2x b64)
        fp16x8 fah[2], fal[2];
        #pragma unroll
        for (int km = 0; km < 2; ++km) {
            int off = (km * 16 + lr) * 36 + q * 8;
            union { fp16x8 v8; fp16x4 v4[2]; } uh, ul;
            uh.v4[0] = *(const fp16x4*)&fh[off];
            uh.v4[1] = *(const fp16x4*)&fh[off + 4];
            ul.v4[0] = *(const fp16x4*)&fl[off];
            ul.v4[1] = *(const fp16x4*)&fl[off + 4];
            fah[km] = uh.v8;
            fal[km] = ul.v8;
        }

        __builtin_amdgcn_s_setprio(1);
        // ns = 0 (contains the 9 score cols): 3-pass hi/lo
        #pragma unroll
        for (int km = 0; km < 2; ++km)
            acc2[km][0] = __builtin_amdgcn_mfma_f32_16x16x32_f16(fah[km], cwh0, acc2[km][0], 0, 0, 0);
        #pragma unroll
        for (int km = 0; km < 2; ++km)
            acc2[km][0] = __builtin_amdgcn_mfma_f32_16x16x32_f16(fah[km], cwl0, acc2[km][0], 0, 0, 0);
        #pragma unroll
        for (int km = 0; km < 2; ++km)
            acc2[km][0] = __builtin_amdgcn_mfma_f32_16x16x32_f16(fal[km], cwh0, acc2[km][0], 0, 0, 0);
        // ns = 1,2 (pure delta cols): 2-pass (w fp16 single, feat hi+lo)
        #pragma unroll
        for (int km = 0; km < 2; ++km)
            acc2[km][1] = __builtin_amdgcn_mfma_f32_16x16x32_f16(fah[km], cwh1, acc2[km][1], 0, 0, 0);
        #pragma unroll
        for (int km = 0; km < 2; ++km)
            acc2[km][1] = __builtin_amdgcn_mfma_f32_16x16x32_f16(fal[km], cwh1, acc2[km][1], 0, 0, 0);
        #pragma unroll
        for (int km = 0; km < 2; ++km)
            acc2[km][2] = __builtin_amdgcn_mfma_f32_16x16x32_f16(fah[km], cwh2, acc2[km][2], 0, 0, 0);
        #pragma unroll
        for (int km = 0; km < 2; ++km)
            acc2[km][2] = __builtin_amdgcn_mfma_f32_16x16x32_f16(fal[km], cwh2, acc2[km][2], 0, 0, 0);
        __builtin_amdgcn_s_setprio(0);

        if (sub < 3) { cwh0 = nwh0; cwl0 = nwl0; cwh1 = nwh1; cwh2 = nwh2; }
    }

    __syncthreads();   // barrier 3: all xs reads AND fbuf reads done; zb overlay safe

    // ---- parallel cross-wave partials: wave w -> zb slice w [32][50] ----
    {
        float* zw = zb + wave * ZB_SLICE;
        #pragma unroll
        for (int km = 0; km < 2; ++km)
            #pragma unroll
            for (int ns = 0; ns < 3; ++ns)
                #pragma unroll
                for (int r = 0; r < 4; ++r) {
                    int row = km * 16 + q * 4 + r;
                    int col = ns * 16 + lr;
                    zw[row * 50 + col] = acc2[km][ns][r];
                }
    }
    __syncthreads();   // barrier 4: partials visible

    // ---- epilogue: sum k-slices (fixed order == old staged reduction),
    //      sigmoid, threshold mask, store ----
    for (int i = tid; i < 32 * 45; i += 256) {
        int m = i / 45;
        int o = i - m * 45;
        int e0 = m * 50 + o;
        float z = ((zb[e0] + zb[ZB_SLICE + e0]) + zb[2 * ZB_SLICE + e0]) + zb[3 * ZB_SLICE + e0];
        float v;
        if (o < 9) {
            v = 1.f / (1.f + expf(-(z + b_cls[o])));
        } else {
            int d = o - 9;
            int a = d >> 2;
            int ea = m * 50 + a;
            float za = ((zb[ea] + zb[ZB_SLICE + ea]) + zb[2 * ZB_SLICE + ea]) + zb[3 * ZB_SLICE + ea];
            float s = 1.f / (1.f + expf(-(za + b_cls[a])));
            v = (s > 0.7f) ? (z + b_reg[d]) : 0.f;
        }
        int mh = m >> 4, mw = m & 15;
        out[(((b * 256 + h0 + mh) * 256) + w0 + mw) * 45 + o] = v;
    }
}

// ---------------------------------------------------------------------------
extern "C" void kernel_launch(void* const* d_in, const int* in_sizes, int n_in,
                              void* d_out, int out_size, void* d_ws, size_t ws_size,
                              hipStream_t stream)
{
    const float* x      = (const float*)d_in[0];
    const float* w_base = (const float*)d_in[1];
    const float* b_base = (const float*)d_in[2];
    const float* w_cls  = (const float*)d_in[3];
    const float* b_cls  = (const float*)d_in[4];
    const float* w_reg  = (const float*)d_in[5];
    const float* b_reg  = (const float*)d_in[6];
    float* out = (float*)d_out;

    _Float16* btI    = (_Float16*)d_ws;
    _Float16* bt2_hi = btI + BT_ELEMS;
    _Float16* bt2_lo = bt2_hi + BT2_ELEMS;

    rpn_prep<<<(BT_ELEMS + BT2_ELEMS + 255) / 256, 256, 0, stream>>>(
        w_base, w_cls, w_reg, btI, bt2_hi, bt2_lo);
    rpn_main<<<8192, 256, 0, stream>>>(
        x, b_base, b_cls, b_reg, btI, bt2_hi, bt2_lo, out);
}